// Round 5
// baseline (1242.839 us; speedup 1.0000x reference)
//
#include <hip/hip_runtime.h>
#include <utility>

// 16-wire statevector sim, batch 128 — single persistent cooperative kernel.
// 256 blocks x 1024 threads, 1 block/CU (128 KiB LDS). 8 barrier groups of 32
// blocks; group g owns batches [16g,16g+16) (2 blocks per batch). No data
// crosses groups, so group barriers suffice (correct for any block placement).
// Wire w <-> global bit (15-w). Per layer l (r=l+1):
//  phase P1: pure-register, group bits {15,14,14-L,13-L}: H2(l-1) ctrl-swaps,
//            Rot{0,1,r,r+1}, CNOT(0->r),(1->r+1)   [L==0: embedding gen]
//  phase P2: chunk fixed bits {15,14}; LDS register sweeps S1{13..10} S2{9..6}
//            S3{5..2} S4{3..0} (+S5 wraps r>=3). L==5: readout fused — wrap
//            CNOTs + H2(5) folded into Z-sign bits, no state write-back.

#define NW    16
#define BLK   1024
#define CHUNK 16384

__device__ unsigned g_bar[8 * 32];   // per-group counters, 128 B apart

// ---------- static_for ----------
template<class F, int... Is>
__device__ __forceinline__ void static_for_impl(F&& f, std::integer_sequence<int, Is...>) {
    (f(std::integral_constant<int, Is>{}), ...);
}
template<int N, class F>
__device__ __forceinline__ void static_for(F&& f) {
    static_for_impl(f, std::make_integer_sequence<int, N>{});
}

__device__ __forceinline__ int swz(int u) { return u ^ ((u >> 4) & 15); }

// ---------- gate primitives ----------
__device__ __forceinline__ void c2x2(float2& a0, float2& a1,
                                     float2 m00, float2 m01,
                                     float2 m10, float2 m11) {
    float2 r0, r1;
    r0.x = m00.x*a0.x - m00.y*a0.y + m01.x*a1.x - m01.y*a1.y;
    r0.y = m00.x*a0.y + m00.y*a0.x + m01.x*a1.y + m01.y*a1.x;
    r1.x = m10.x*a0.x - m10.y*a0.y + m11.x*a1.x - m11.y*a1.y;
    r1.y = m10.x*a0.y + m10.y*a0.x + m11.x*a1.y + m11.y*a1.x;
    a0 = r0; a1 = r1;
}

template<int Q>
__device__ __forceinline__ void rot_regs(float2 a[16], float2 m00, float2 m01,
                                         float2 m10, float2 m11) {
#pragma unroll
    for (int j = 0; j < 16; ++j)
        if (!((j >> Q) & 1))
            c2x2(a[j], a[j | (1 << Q)], m00, m01, m10, m11);
}

template<int QC, int QT>
__device__ __forceinline__ void cnot_inreg(float2 a[16]) {
#pragma unroll
    for (int j = 0; j < 16; ++j)
        if (((j >> QC) & 1) && !((j >> QT) & 1)) {
            float2 t = a[j]; a[j] = a[j | (1 << QT)]; a[j | (1 << QT)] = t;
        }
}

template<int QT>
__device__ __forceinline__ void cnot_ctrlout(float2 a[16], int ctrl) {
#pragma unroll
    for (int j = 0; j < 16; ++j)
        if (!((j >> QT) & 1)) {
            int j2 = j | (1 << QT);
            float2 x = a[j], y = a[j2];
            a[j].x  = ctrl ? y.x : x.x;  a[j].y  = ctrl ? y.y : x.y;
            a[j2].x = ctrl ? x.x : y.x;  a[j2].y = ctrl ? x.y : y.y;
        }
}

// Rot(phi,theta,omega) = RZ(omega) RY(theta) RZ(phi)
__device__ __forceinline__ void rot_mat(const float* ww, float2 m[4]) {
    float phi = ww[0], th = ww[1], om = ww[2];
    float ct, st;   sincosf(0.5f * th, &st, &ct);
    float cap, sap; sincosf(0.5f * (phi + om), &sap, &cap);
    float cam, sam; sincosf(0.5f * (phi - om), &sam, &cam);
    m[0] = make_float2( cap * ct, -sap * ct);
    m[1] = make_float2(-cam * st, -sam * st);
    m[2] = make_float2( cam * st, -sam * st);
    m[3] = make_float2( cap * ct,  sap * ct);
}

// ---------- pass2 sweep gate driver (validated R4 schedule) ----------
template<int L, int S>
__device__ __forceinline__ int sweep_gates(float2 a[16], const float2 (*gm)[4], int ub) {
    constexpr int r = L + 1;
    constexpr int base = (S == 2) ? 6 : (S == 3) ? 2 : (S == 4) ? 0 : 10;
    int wmask = 0;
    if constexpr (S <= 4) {
        constexpr int plo = (S == 1) ? 10 : (S == 2) ? 6 : (S == 3) ? 2 : 0;
        constexpr int phi = (S == 1) ? 13 : (S == 2) ? 9 : (S == 3) ? 5 : 1;
        static_for<phi - plo + 1>([&](auto K) {
            constexpr int bb = phi - decltype(K)::value;
            if constexpr (bb != 15 - r && bb != 14 - r) {
                constexpr int wire = 15 - bb;
                rot_regs<bb - base>(a, gm[wire][0], gm[wire][1], gm[wire][2], gm[wire][3]);
            }
        });
        static_for<14 - r>([&](auto K) {
            constexpr int i  = 2 + decltype(K)::value;
            constexpr int cb = 15 - i, tb = cb - r;
            if constexpr (tb >= plo && tb <= phi) {
                if constexpr (cb <= base + 3) {
                    cnot_inreg<cb - base, tb - base>(a);
                } else if constexpr (tb - r >= plo) {
                    cnot_ctrlout<tb - base>(a, (ub >> cb) & 1);
                } else {
                    wmask |= ((ub >> cb) & 1) << (tb - base);
                }
            }
        });
    } else {
        static_for<(r >= 3) ? (r - 2) : 0>([&](auto K) {
            constexpr int i  = 18 - r + decltype(K)::value;
            constexpr int cb = 15 - i, tb = 31 - i - r;
            cnot_ctrlout<tb - 10>(a, (ub >> cb) & 1);
        });
    }
    return wmask;
}

// ---------- P1: pure register, group bits {15,14,g1,g0} ----------
template<int L>
__device__ void pass1_task(const float* __restrict__ x, const float* __restrict__ w,
                           float2* __restrict__ gb, int b, int m) {
    constexpr int r  = L + 1;
    constexpr int g1 = (L == 0) ? 13 : 14 - L;
    constexpr int g0 = (L == 0) ? 12 : 13 - L;
    const int T = (m << 10) | (int)threadIdx.x;   // 12-bit task index

    int sb;
    {
        int lo = T & ((1 << g0) - 1);
        int hi = T >> g0;
        sb = lo | (hi << (g1 + 1));               // g1 = g0+1 (adjacent)
    }

    float2 m0[4], m1[4], mr[4], mr1[4];
    rot_mat(w + (L * NW + 0) * 3, m0);
    rot_mat(w + (L * NW + 1) * 3, m1);
    if constexpr (L == 0) {
        rot_mat(w + 2 * 3, mr);
    } else {
        rot_mat(w + (L * NW + r) * 3, mr);
        rot_mat(w + (L * NW + r + 1) * 3, mr1);
    }

    float2 a[16];
    if constexpr (L == 0) {
        float cv[NW], sv[NW];
#pragma unroll
        for (int wq = 0; wq < NW; ++wq)
            sincosf(0.5f * x[b * NW + wq], &sv[wq], &cv[wq]);
        float common = 1.0f;
#pragma unroll
        for (int wq = 4; wq < NW; ++wq) {
            int bit = (sb >> (15 - wq)) & 1;
            common *= bit ? sv[wq] : cv[wq];
        }
#pragma unroll
        for (int j = 0; j < 16; ++j) {
            float f0 = (j & 8) ? sv[0] : cv[0];
            float f1 = (j & 4) ? sv[1] : cv[1];
            float f2 = (j & 2) ? sv[2] : cv[2];
            float f3 = (j & 1) ? sv[3] : cv[3];
            a[j] = make_float2(common * f0 * f1 * f2 * f3, 0.0f);
        }
    } else {
#pragma unroll
        for (int j = 0; j < 16; ++j) {
            int s = sb | ((j & 1) << g0) | (((j >> 1) & 1) << g1)
                       | (((j >> 2) & 1) << 14) | (((j >> 3) & 1) << 15);
            a[j] = gb[s];
        }
        if constexpr (L >= 2) {
            cnot_ctrlout<3>(a, (sb >> (L - 1)) & 1);
            cnot_ctrlout<2>(a, (sb >> (L - 2)) & 1);
        } else {
            cnot_ctrlout<3>(a, sb & 1);
        }
    }

    rot_regs<3>(a, m0[0], m0[1], m0[2], m0[3]);
    rot_regs<2>(a, m1[0], m1[1], m1[2], m1[3]);
    if constexpr (L == 0) {
        rot_regs<1>(a, mr[0], mr[1], mr[2], mr[3]);
        cnot_inreg<3, 2>(a);
        cnot_inreg<2, 1>(a);
    } else {
        rot_regs<1>(a, mr[0],  mr[1],  mr[2],  mr[3]);
        rot_regs<0>(a, mr1[0], mr1[1], mr1[2], mr1[3]);
        cnot_inreg<3, 1>(a);
        cnot_inreg<2, 0>(a);
    }

#pragma unroll
    for (int j = 0; j < 16; ++j) {
        int s = sb | ((j & 1) << g0) | (((j >> 1) & 1) << g1)
                   | (((j >> 2) & 1) << 14) | (((j >> 3) & 1) << 15);
        gb[s] = a[j];
    }
}

// ---------- P2: LDS-staged register sweeps on one 2^14 chunk ----------
template<int L>
__device__ void pass2_chunk(float2* __restrict__ gb, int c, const float2 (*gm)[4],
                            float2* lds, float* accs) {
    constexpr int r = L + 1;
    const int tid = threadIdx.x;
    float2* g = gb + ((size_t)c << 14);
    float2 a[16];

    const int ub1 = tid;
#pragma unroll
    for (int j = 0; j < 16; ++j) a[j] = g[ub1 | (j << 10)];
    __syncthreads();          // LDS free of previous chunk's readers
    {
        int wm = sweep_gates<L, 1>(a, gm, ub1) << 10;
#pragma unroll
        for (int j = 0; j < 16; ++j) lds[swz((ub1 | (j << 10)) ^ wm)] = a[j];
    }
    __syncthreads();
    {
        const int ub = (tid & 63) | ((tid >> 6) << 10);
#pragma unroll
        for (int j = 0; j < 16; ++j) a[j] = lds[swz(ub | (j << 6))];
        int wm = sweep_gates<L, 2>(a, gm, ub) << 6;
#pragma unroll
        for (int j = 0; j < 16; ++j) lds[swz((ub | (j << 6)) ^ wm)] = a[j];
    }
    __syncthreads();
    {
        const int ub = (tid & 3) | ((tid >> 2) << 6);
#pragma unroll
        for (int j = 0; j < 16; ++j) a[j] = lds[swz(ub | (j << 2))];
        int wm = sweep_gates<L, 3>(a, gm, ub) << 2;
#pragma unroll
        for (int j = 0; j < 16; ++j) lds[swz((ub | (j << 2)) ^ wm)] = a[j];
    }
    __syncthreads();
    {
        const int ub = tid << 4;
#pragma unroll
        for (int j = 0; j < 16; ++j) a[j] = lds[swz(ub | j)];
        int wm = sweep_gates<L, 4>(a, gm, ub);
#pragma unroll
        for (int j = 0; j < 16; ++j) lds[swz((ub | j) ^ wm)] = a[j];
    }
    __syncthreads();

    if constexpr (L == 5) {
        // Fused readout: r=6 wrap CNOTs (ctrl bits 3..0 -> tgt bits 13..10)
        // and H2(5) (ctrl bits 5,4 -> tgt bits 15,14) folded into signs.
        const int ub = tid;
        float psum = 0.f, z2s = 0.f, z3s = 0.f, z4s = 0.f, z5s = 0.f;
#pragma unroll
        for (int j = 0; j < 16; ++j) {
            float2 v = lds[swz(ub | (j << 10))];
            float p = v.x * v.x + v.y * v.y;
            psum += p;
            z2s += (j & 8) ? -p : p;
            z3s += (j & 4) ? -p : p;
            z4s += (j & 2) ? -p : p;
            z5s += (j & 1) ? -p : p;
        }
        float z[NW];
        z[0] = (((c >> 1) ^ (tid >> 5)) & 1) ? -psum : psum;
        z[1] = (((c) ^ (tid >> 4)) & 1) ? -psum : psum;
        z[2] = ((tid >> 3) & 1) ? -z2s : z2s;
        z[3] = ((tid >> 2) & 1) ? -z3s : z3s;
        z[4] = ((tid >> 1) & 1) ? -z4s : z4s;
        z[5] = (tid & 1) ? -z5s : z5s;
#pragma unroll
        for (int i = 6; i < NW; ++i)
            z[i] = ((tid >> (15 - i)) & 1) ? -psum : psum;
#pragma unroll
        for (int i = 0; i < NW; ++i) {
            float v = z[i];
#pragma unroll
            for (int off = 32; off > 0; off >>= 1) v += __shfl_down(v, off, 64);
            if ((tid & 63) == 0) atomicAdd(&accs[i], v);
        }
    } else if constexpr (r >= 3) {
        const int ub = tid;
#pragma unroll
        for (int j = 0; j < 16; ++j) a[j] = lds[swz(ub | (j << 10))];
        (void)sweep_gates<L, 5>(a, gm, ub);
#pragma unroll
        for (int j = 0; j < 16; ++j) g[ub | (j << 10)] = a[j];
    } else {
#pragma unroll
        for (int it = 0; it < 8; ++it) {
            int v = tid + it * BLK;
            int u = 2 * v;
            float2 lo = lds[swz(u)];
            float2 hi = lds[swz(u + 1)];
            reinterpret_cast<float4*>(g)[v] = make_float4(lo.x, lo.y, hi.x, hi.y);
        }
    }
}

// ---------- group barrier (32 blocks per group, monotone counter) ----------
__device__ __forceinline__ void group_barrier(int grp, unsigned target) {
    __syncthreads();
    if (threadIdx.x == 0) {
        __threadfence();
        __hip_atomic_fetch_add(&g_bar[grp * 32], 1u, __ATOMIC_RELAXED,
                               __HIP_MEMORY_SCOPE_AGENT);
        while (__hip_atomic_load(&g_bar[grp * 32], __ATOMIC_RELAXED,
                                 __HIP_MEMORY_SCOPE_AGENT) < target)
            __builtin_amdgcn_s_sleep(2);
        __threadfence();
    }
    __syncthreads();
}

// ---------- the fused kernel ----------
__global__ __launch_bounds__(BLK)
void qfused(const float* __restrict__ x, const float* __restrict__ w,
            float* __restrict__ out, float2* __restrict__ psi, int batch) {
    __shared__ float2 lds[CHUNK];
    __shared__ float2 gm[NW][4];
    __shared__ float  accs[NW];

    const int B = blockIdx.x;
    const int grp = B & 7, jj = B >> 3;
    const int b  = grp * 16 + (jj >> 1);
    const int m0 = (jj & 1) * 2;
    const bool active = (b < batch);
    float2* gb = psi + ((size_t)b << 16);
    unsigned bt = 0;

    static_for<6>([&](auto LC) {
        constexpr int L = decltype(LC)::value;

        if (active) {
            pass1_task<L>(x, w, gb, b, m0);
            pass1_task<L>(x, w, gb, b, m0 + 1);
        }
        bt += 32; group_barrier(grp, bt);

        // per-layer gate matrices into LDS (all blocks; uniform)
        if (threadIdx.x < NW) rot_mat(w + (L * NW + (int)threadIdx.x) * 3, gm[threadIdx.x]);
        if (L == 5 && threadIdx.x < NW) accs[threadIdx.x] = 0.f;
        __syncthreads();

        if (active) {
            pass2_chunk<L>(gb, m0,     gm, lds, accs);
            pass2_chunk<L>(gb, m0 + 1, gm, lds, accs);
        }
        if (L < 5) { bt += 32; group_barrier(grp, bt); }
    });

    __syncthreads();
    if (active && threadIdx.x < NW)
        atomicAdd(&out[b * NW + threadIdx.x], accs[threadIdx.x]);
}

extern "C" void kernel_launch(void* const* d_in, const int* in_sizes, int n_in,
                              void* d_out, int out_size, void* d_ws, size_t ws_size,
                              hipStream_t stream) {
    const float* x = (const float*)d_in[0];   // (B, 16) float32
    const float* w = (const float*)d_in[1];   // (6, 16, 3) float32
    float* out = (float*)d_out;               // (B, 16) float32
    float2* psi = (float2*)d_ws;              // B * 65536 * 8 B = 64 MiB
    int batch = in_sizes[0] / NW;

    // zero the output (atomicAdd accumulation) and the barrier counters
    hipMemsetAsync(d_out, 0, (size_t)out_size * sizeof(float), stream);
    void* barPtr = nullptr;
    hipGetSymbolAddress(&barPtr, HIP_SYMBOL(g_bar));
    hipMemsetAsync(barPtr, 0, sizeof(unsigned) * 8 * 32, stream);

    void* args[] = { (void*)&x, (void*)&w, (void*)&out, (void*)&psi, (void*)&batch };
    hipLaunchCooperativeKernel((const void*)qfused, dim3(256), dim3(BLK),
                               args, 0, stream);
}